// Round 1
// 1164.446 us; speedup vs baseline: 1.1028x; 1.1028x over previous
//
#include <hip/hip_runtime.h>
#include <cstdint>
#include <cstddef>

#define B_DIM 2048
#define I_DIM 20000
#define IPAD 20480   // encoder-L1 K padded to multiple of 128 (8 x 2560)
#define NPAD 20224   // heads-L2 N padded to multiple of 256 (79 x 256)
#define D_DIM 512
#define H_DIM 1024   // 2*D

typedef __bf16 bf16x8 __attribute__((ext_vector_type(8)));
typedef float f32x4 __attribute__((ext_vector_type(4)));

__device__ __forceinline__ unsigned short f2bf(float f) {
  union { float f; unsigned u; } v; v.f = f;
  unsigned u = v.u;
  u += 0x7fffu + ((u >> 16) & 1u);  // RNE (finite inputs)
  return (unsigned short)(u >> 16);
}
__device__ __forceinline__ float bf2f(unsigned short h) {
  union { unsigned u; float f; } v; v.u = ((unsigned)h) << 16;
  return v.f;
}

// async global->LDS, 16B per lane; lds dest = wave-uniform base + lane*16
__device__ __forceinline__ void glds16(const unsigned short* g, unsigned short* l) {
  __builtin_amdgcn_global_load_lds(
      (const __attribute__((address_space(1))) void*)g,
      (__attribute__((address_space(3))) void*)l, 16, 0, 0);
}

// ---------------------------------------------------------------------------
// Fused: noisy = mask ? 0 : likes (bf16, K-padded to IPAD with zeros),
// popular += colsum(likes)/B. grid: (IPAD/4/256, B/64), 256 thr.
__global__ void noisy_popular_kernel(const float* __restrict__ likes,
                                     const int* __restrict__ mask,
                                     unsigned short* __restrict__ noisy,
                                     float* __restrict__ pop) {
  int idx4 = blockIdx.x * 256 + threadIdx.x;  // float4 column index, < IPAD/4
  int r0 = blockIdx.y * 64;
  if (idx4 >= I_DIM / 4) {  // zero pad region [5000, 5120)
    ushort4 z = make_ushort4(0, 0, 0, 0);
    for (int r = 0; r < 64; ++r)
      ((ushort4*)noisy)[(size_t)(r0 + r) * (IPAD / 4) + idx4] = z;
    return;
  }
  float4 s = make_float4(0.f, 0.f, 0.f, 0.f);
  for (int r = 0; r < 64; ++r) {
    size_t inoff = (size_t)(r0 + r) * (I_DIM / 4) + idx4;
    float4 L = ((const float4*)likes)[inoff];
    int4 M = ((const int4*)mask)[inoff];
    s.x += L.x; s.y += L.y; s.z += L.z; s.w += L.w;
    ushort4 o;
    o.x = M.x ? (unsigned short)0 : f2bf(L.x);
    o.y = M.y ? (unsigned short)0 : f2bf(L.y);
    o.z = M.z ? (unsigned short)0 : f2bf(L.z);
    o.w = M.w ? (unsigned short)0 : f2bf(L.w);
    ((ushort4*)noisy)[(size_t)(r0 + r) * (IPAD / 4) + idx4] = o;
  }
  const float inv = 1.0f / B_DIM;
  atomicAdd(&pop[idx4 * 4 + 0], s.x * inv);
  atomicAdd(&pop[idx4 * 4 + 1], s.y * inv);
  atomicAdd(&pop[idx4 * 4 + 2], s.z * inv);
  atomicAdd(&pop[idx4 * 4 + 3], s.w * inv);
}

// ---------------------------------------------------------------------------
// transpose f32 [Rvalid,C] -> bf16 [C,Rpad] (rows >= Rvalid written as 0)
__global__ void transpose_to_bf16(const float* __restrict__ in,
                                  unsigned short* __restrict__ out, int Rpad,
                                  int C, int Rvalid) {
  __shared__ unsigned short tile[32][33];
  int c0 = blockIdx.x * 32, r0 = blockIdx.y * 32;
  int tx = threadIdx.x, ty = threadIdx.y;  // 32 x 8
#pragma unroll
  for (int i = 0; i < 4; i++) {
    int r = r0 + ty + i * 8;
    tile[ty + i * 8][tx] =
        (r < Rvalid) ? f2bf(in[(size_t)r * C + c0 + tx]) : (unsigned short)0;
  }
  __syncthreads();
#pragma unroll
  for (int i = 0; i < 4; i++) {
    int c = c0 + ty + i * 8;
    out[(size_t)c * Rpad + r0 + tx] = tile[tx][ty + i * 8];
  }
}

// ---------------------------------------------------------------------------
__global__ void concat_bias_kernel(const float* __restrict__ a,
                                   const float* __restrict__ b,
                                   float* __restrict__ out) {
  int i = blockIdx.x * 256 + threadIdx.x;
  if (i < H_DIM) out[i] = a[i];
  else if (i < 2 * H_DIM) out[i] = b[i - H_DIM];
}

// ---------------------------------------------------------------------------
// h1 = bf16(relu(sum_z partial[z] + bias))   partial: [Z][B][H] f32
template <int Z>
__global__ void reduce_relu_kernel(const float* __restrict__ partial,
                                   const float* __restrict__ bias,
                                   unsigned short* __restrict__ h1) {
  int idx4 = blockIdx.x * 256 + threadIdx.x;  // float4 index over B*H/4
  const size_t slice = (size_t)B_DIM * H_DIM / 4;
  float4 s = ((const float4*)partial)[idx4];
#pragma unroll
  for (int z = 1; z < Z; z++) {
    float4 p = ((const float4*)partial)[z * slice + idx4];
    s.x += p.x; s.y += p.y; s.z += p.z; s.w += p.w;
  }
  float4 b = ((const float4*)bias)[idx4 & (H_DIM / 4 - 1)];
  ushort4 o;
  o.x = f2bf(fmaxf(s.x + b.x, 0.f));
  o.y = f2bf(fmaxf(s.y + b.y, 0.f));
  o.z = f2bf(fmaxf(s.z + b.z, 0.f));
  o.w = f2bf(fmaxf(s.w + b.w, 0.f));
  ((ushort4*)h1)[idx4] = o;
}

// ---------------------------------------------------------------------------
// L2-normalize rows of embed (bf16 [B, D]) -> normed (bf16)
__global__ void l2norm_kernel(const unsigned short* __restrict__ embed,
                              unsigned short* __restrict__ normed) {
  int row = blockIdx.x * 4 + (threadIdx.x >> 6);
  int lane = threadIdx.x & 63;
  const unsigned short* e = embed + (size_t)row * D_DIM;
  float v[8];
  float ss = 0.f;
#pragma unroll
  for (int j = 0; j < 8; j++) { v[j] = bf2f(e[lane + j * 64]); ss += v[j] * v[j]; }
#pragma unroll
  for (int o = 32; o > 0; o >>= 1) ss += __shfl_xor(ss, o, 64);
  float s = rsqrtf(fmaxf(ss, 1e-12f));
  unsigned short* nr = normed + (size_t)row * D_DIM;
#pragma unroll
  for (int j = 0; j < 8; j++) nr[lane + j * 64] = f2bf(v[j] * s);
}

// ---------------------------------------------------------------------------
// m97-structure GEMM (kept for the small GEMMs): C = act(A @ BT^T + bias)
// 128x128 tile, BK=32, 4 waves.
template <int ACT, bool OBF16>
__global__ __launch_bounds__(256) void gemm128(
    const unsigned short* __restrict__ A, const unsigned short* __restrict__ BT,
    const float* __restrict__ bias, void* __restrict__ Cout,
    int N, int lda, int ldb, int ldc, int kLen, long long zStride) {
  __shared__ unsigned short As[128 * 32];
  __shared__ unsigned short Bs[128 * 32];
  const int n0 = blockIdx.x * 128;
  const int m0 = blockIdx.y * 128;
  const int t = threadIdx.x;
  const int lane = t & 63;
  const int wv = t >> 6;
  const int quad = lane >> 4;
  const int tc = lane & 15;
  const int wm = (wv >> 1) * 64;
  const int wn = (wv & 1) * 64;
  const int k0 = blockIdx.z * kLen;

  f32x4 acc[4][4];
#pragma unroll
  for (int i = 0; i < 4; i++)
#pragma unroll
    for (int j = 0; j < 4; j++) acc[i][j] = (f32x4){0.f, 0.f, 0.f, 0.f};

  const int srow = lane >> 2;
  const int skch = (lane & 3) * 8;
  const unsigned short* gA0 = A + (size_t)(m0 + wv * 32 + srow) * lda + k0 + skch;
  const unsigned short* gA1 = gA0 + (size_t)16 * lda;
  const unsigned short* gB0 = BT + (size_t)(n0 + wv * 32 + srow) * ldb + k0 + skch;
  const unsigned short* gB1 = gB0 + (size_t)16 * ldb;
  unsigned short* lA = As + wv * 1024;
  unsigned short* lB = Bs + wv * 1024;

  const int nIter = kLen >> 5;
  for (int it = 0; it < nIter; ++it) {
    __syncthreads();
    glds16(gA0, lA);
    glds16(gA1, lA + 512);
    glds16(gB0, lB);
    glds16(gB1, lB + 512);
    gA0 += 32; gA1 += 32; gB0 += 32; gB1 += 32;
    __syncthreads();
    bf16x8 a[4], b[4];
#pragma unroll
    for (int i = 0; i < 4; i++) {
      a[i] = *(const bf16x8*)&As[(wm + i * 16 + tc) * 32 + quad * 8];
      b[i] = *(const bf16x8*)&Bs[(wn + i * 16 + tc) * 32 + quad * 8];
    }
#pragma unroll
    for (int i = 0; i < 4; i++)
#pragma unroll
      for (int j = 0; j < 4; j++)
        acc[i][j] =
            __builtin_amdgcn_mfma_f32_16x16x32_bf16(a[i], b[j], acc[i][j], 0, 0, 0);
  }

  float* outF = (float*)Cout + (size_t)blockIdx.z * zStride;
  unsigned short* outH = (unsigned short*)Cout;
#pragma unroll
  for (int j = 0; j < 4; j++) {
    int col = n0 + wn + j * 16 + tc;
    if (col >= N) continue;
    float bv = bias ? bias[col] : 0.f;
#pragma unroll
    for (int i = 0; i < 4; i++) {
      int row0 = m0 + wm + i * 16 + quad * 4;
#pragma unroll
      for (int r = 0; r < 4; r++) {
        float v = acc[i][j][r] + bv;
        if (ACT == 1) v = fmaxf(v, 0.f);
        else if (ACT == 2) v = 1.f / (1.f + __expf(-v));
        else if (ACT == 3) v = -v;
        if (OBF16)
          outH[(size_t)(row0 + r) * ldc + col] = f2bf(v);
        else
          outF[(size_t)(row0 + r) * ldc + col] = v;
      }
    }
  }
}

// ---------------------------------------------------------------------------
// 256x256 8-phase GEMM (m201-style: T2 LDS XOR-swizzle + T3/T4 counted vmcnt
// + T5 setprio). BK=64, 8 waves (2Mx4N), 128 KiB dynamic LDS, 2 K-tiles/iter.
// LDS ring: buf{0,1} x {A0,A1,B0,B1} 16KB half-tile slots; even K-tiles in
// buf0, odd in buf1 (no swap). Staging via global_load_lds with PRE-SWIZZLED
// global source (slot ^= row&7) so linear LDS dest receives swizzled layout
// (rule #21: both-sides-or-neither); ds_read applies the same XOR.
// Requires: M%256==0, BT padded to 256-row blocks, kLen%128==0, rows 16B-aligned.
template <int ACT, bool OBF16>
__global__ __launch_bounds__(512, 2) void gemm256(
    const unsigned short* __restrict__ A, const unsigned short* __restrict__ BT,
    const float* __restrict__ bias, void* __restrict__ Cout,
    int N, int lda, int ldb, int ldc, int kLen, long long zStride) {
  extern __shared__ unsigned short lds[];
  const int n0 = blockIdx.x * 256;
  const int m0 = blockIdx.y * 256;
  const int t = threadIdx.x;
  const int L = t & 63;
  const int w = t >> 6;
  const int quad = L >> 4;
  const int tc = L & 15;
  const int wm = (w >> 2) * 128;  // 0 / 128
  const int wn = (w & 3) * 64;    // 0,64,128,192
  const int k0 = blockIdx.z * kLen;

  // staging: per phase the block stages one 128x64 half-tile (16 KB).
  // wave w covers rows [w*16, w*16+16); lane L -> row +(L>>3), 16B slot (L&7),
  // global slot pre-swizzled by ^ (row&7) = ^(L>>3).
  const int srow = L >> 3;
  const int scol = ((L & 7) ^ srow) * 8;  // elems
  size_t aOff[2][2], bOff[2][2];
#pragma unroll
  for (int h = 0; h < 2; h++)
#pragma unroll
    for (int c = 0; c < 2; c++) {
      aOff[h][c] = (size_t)(m0 + h * 128 + w * 16 + c * 8 + srow) * lda + k0 + scol;
      bOff[h][c] = (size_t)(n0 + h * 128 + w * 16 + c * 8 + srow) * ldb + k0 + scol;
    }
  const int stageW = w * 1024;  // ushorts (16 rows x 64)
  const int BO1 = 32768;        // buf1 offset (64 KB)

  const int aR0 = (wm >> 7) * 8192;          // own A-half slot, buf0
  const int aR1 = BO1 + aR0;
  const int bR0 = 16384 + (wn >> 7) * 8192;  // own B-half slot, buf0
  const int bR1 = BO1 + bR0;
  const int swz = (tc & 7) << 3;  // read-side XOR (row&7 == tc&7 for frag rows)

  f32x4 acc[8][4];
#pragma unroll
  for (int i = 0; i < 8; i++)
#pragma unroll
    for (int j = 0; j < 4; j++) acc[i][j] = (f32x4){0.f, 0.f, 0.f, 0.f};

  bf16x8 aF[4][2], bF0[2][2], bF1[2][2];

#define STAGE_A(h, kt, bo)                                                        \
  do {                                                                            \
    glds16(A + aOff[h][0] + (size_t)(kt) * 64, lds + (bo) + (h) * 8192 + stageW); \
    glds16(A + aOff[h][1] + (size_t)(kt) * 64,                                    \
           lds + (bo) + (h) * 8192 + stageW + 512);                               \
  } while (0)
#define STAGE_B(h, kt, bo)                                                        \
  do {                                                                            \
    glds16(BT + bOff[h][0] + (size_t)(kt) * 64,                                   \
           lds + (bo) + 16384 + (h) * 8192 + stageW);                             \
    glds16(BT + bOff[h][1] + (size_t)(kt) * 64,                                   \
           lds + (bo) + 16384 + (h) * 8192 + stageW + 512);                       \
  } while (0)

  auto RD_A = [&](int base, int i0) {
#pragma unroll
    for (int ii = 0; ii < 4; ii++) {
      const int row = (i0 + ii) * 16 + tc;
#pragma unroll
      for (int ks = 0; ks < 2; ks++)
        aF[ii][ks] =
            *(const bf16x8*)&lds[base + row * 64 + (((ks * 4 + quad) * 8) ^ swz)];
    }
  };
  auto RD_B = [&](int base, int jg, bf16x8(&bF)[2][2]) {
#pragma unroll
    for (int jj = 0; jj < 2; jj++) {
      const int row = (wn & 64) + (jg * 2 + jj) * 16 + tc;
#pragma unroll
      for (int ks = 0; ks < 2; ks++)
        bF[jj][ks] =
            *(const bf16x8*)&lds[base + row * 64 + (((ks * 4 + quad) * 8) ^ swz)];
    }
  };
  auto MM = [&](int ig, bf16x8(&bF)[2][2], int jg) {
#pragma unroll
    for (int ii = 0; ii < 4; ii++)
#pragma unroll
      for (int jj = 0; jj < 2; jj++)
#pragma unroll
        for (int ks = 0; ks < 2; ks++)
          acc[ig * 4 + ii][jg * 2 + jj] = __builtin_amdgcn_mfma_f32_16x16x32_bf16(
              aF[ii][ks], bF[jj][ks], acc[ig * 4 + ii][jg * 2 + jj], 0, 0, 0);
  };

#define PH_MID()                                      \
  __builtin_amdgcn_s_barrier();                       \
  asm volatile("s_waitcnt lgkmcnt(0)" ::: "memory");  \
  __builtin_amdgcn_sched_barrier(0);                  \
  __builtin_amdgcn_s_setprio(1)
#define PH_END()                                      \
  __builtin_amdgcn_s_setprio(0);                      \
  __builtin_amdgcn_sched_barrier(0);                  \
  __builtin_amdgcn_s_barrier()
#define VMW4() asm volatile("s_waitcnt vmcnt(4)" ::: "memory")

  const int nT = kLen >> 6;   // K-tiles of 64 (even)
  const int nIt = nT >> 1;

  // prologue: tile0 A+B -> buf0, tile1 B -> buf1; allow tile1-B in flight
  STAGE_A(0, 0, 0); STAGE_A(1, 0, 0); STAGE_B(0, 0, 0); STAGE_B(1, 0, 0);
  STAGE_B(0, 1, BO1); STAGE_B(1, 1, BO1);
  VMW4();
  __builtin_amdgcn_s_barrier();

#pragma unroll 1
  for (int it = 0; it < nIt; ++it) {
    const int T = it << 1;
    const int ktA1 = T + 1;                         // always valid
    const int kt2 = (T + 2 < nT) ? T + 2 : nT - 1;  // tail: dummy re-stage
    const int kt3 = (T + 3 < nT) ? T + 3 : nT - 1;
    // p0: compute T (buf0) quadrant i0-3 x j0-1
    RD_A(aR0, 0); RD_B(bR0, 0, bF0);
    STAGE_A(0, ktA1, BO1);
    PH_MID(); MM(0, bF0, 0); PH_END();
    // p1: i0-3 x j2-3
    RD_B(bR0, 1, bF1);
    STAGE_A(1, ktA1, BO1);
    PH_MID(); MM(0, bF1, 1); PH_END();
    // p2: i4-7 x j0-1   (T's B0 reads finished end-p1 -> safe to stage B into buf0)
    RD_A(aR0, 4);
    STAGE_B(0, kt2, 0);
    PH_MID(); MM(1, bF0, 0); PH_END();
    // p3: i4-7 x j2-3; counted wait: T+1's A (p0/p1) + B (prev p6/p7) landed
    STAGE_B(1, kt2, 0);
    PH_MID(); MM(1, bF1, 1); VMW4(); PH_END();
    // p4: compute T+1 (buf1) i0-3 x j0-1  (T's A reads finished end-p2)
    RD_A(aR1, 0); RD_B(bR1, 0, bF0);
    STAGE_A(0, kt2, 0);
    PH_MID(); MM(0, bF0, 0); PH_END();
    // p5: i0-3 x j2-3
    RD_B(bR1, 1, bF1);
    STAGE_A(1, kt2, 0);
    PH_MID(); MM(0, bF1, 1); PH_END();
    // p6: i4-7 x j0-1  (T+1's B reads finished end-p5 -> stage B into buf1)
    RD_A(aR1, 4);
    STAGE_B(0, kt3, BO1);
    PH_MID(); MM(1, bF0, 0); PH_END();
    // p7: i4-7 x j2-3; counted wait: T+2's B (p2/p3) + A (p4/p5) landed
    STAGE_B(1, kt3, BO1);
    PH_MID(); MM(1, bF1, 1); VMW4(); PH_END();
  }
#undef STAGE_A
#undef STAGE_B
#undef PH_MID
#undef PH_END
#undef VMW4

  float* outF = (float*)Cout + (size_t)blockIdx.z * zStride;
  unsigned short* outH = (unsigned short*)Cout;
#pragma unroll
  for (int j = 0; j < 4; j++) {
    const int col = n0 + wn + j * 16 + tc;
    if (col >= N) continue;
    const float bv = bias ? bias[col] : 0.f;
#pragma unroll
    for (int i = 0; i < 8; i++) {
      const int row0 = m0 + wm + i * 16 + quad * 4;
#pragma unroll
      for (int r = 0; r < 4; r++) {
        float v = acc[i][j][r] + bv;
        if (ACT == 1) v = fmaxf(v, 0.f);
        else if (ACT == 2) v = 1.f / (1.f + __expf(-v));
        else if (ACT == 3) v = -v;
        if (OBF16)
          outH[(size_t)(row0 + r) * ldc + col] = f2bf(v);
        else
          outF[(size_t)(row0 + r) * ldc + col] = v;
      }
    }
  }
}

// ---------------------------------------------------------------------------
extern "C" void kernel_launch(void* const* d_in, const int* in_sizes, int n_in,
                              void* d_out, int out_size, void* d_ws, size_t ws_size,
                              hipStream_t stream) {
  const float* likes = (const float*)d_in[1];
  const int* mask = (const int*)d_in[2];
  const float* enc_w1 = (const float*)d_in[3];
  const float* enc_b1 = (const float*)d_in[4];
  const float* enc_w2 = (const float*)d_in[5];
  const float* enc_b2 = (const float*)d_in[6];
  const float* lk_w1 = (const float*)d_in[7];
  const float* lk_b1 = (const float*)d_in[8];
  const float* lk_w2 = (const float*)d_in[9];
  const float* lk_b2 = (const float*)d_in[10];
  const float* rc_w1 = (const float*)d_in[11];
  const float* rc_b1 = (const float*)d_in[12];
  const float* rc_w2 = (const float*)d_in[13];
  const float* rc_b2 = (const float*)d_in[14];

  float* out_likes = (float*)d_out;
  float* out_sim = out_likes + (size_t)B_DIM * I_DIM;
  float* out_rec = out_sim + (size_t)B_DIM * B_DIM;
  float* out_pop = out_rec + (size_t)B_DIM * I_DIM;

  // ws layout (ushort units). A_noisy region reused by LK2T/RC2T after G1.
  unsigned short* ws = (unsigned short*)d_ws;
  unsigned short* A_noisy = ws;                              // 2048 x 20480
  unsigned short* LK2T = ws;                                 // 20224 x 1024
  unsigned short* RC2T = ws + (size_t)NPAD * H_DIM;          // 20224 x 1024
  unsigned short* W1T = ws + (size_t)B_DIM * IPAD;           // 1024 x 20480
  unsigned short* W2T = W1T + (size_t)H_DIM * IPAD;          // 512 x 1024
  unsigned short* W1catT = W2T + (size_t)D_DIM * H_DIM;      // 2048 x 512
  float* bcat = (float*)(W1catT + (size_t)2 * H_DIM * D_DIM);  // 2048 f32
  unsigned short* h1 = W1catT + (size_t)2 * H_DIM * D_DIM + 2 * H_DIM * 2;
  unsigned short* hboth = h1 + (size_t)B_DIM * H_DIM;        // 2048 x 2048
  unsigned short* embed = hboth + (size_t)B_DIM * 2 * H_DIM; // 2048 x 512
  unsigned short* normed = embed + (size_t)B_DIM * D_DIM;    // 2048 x 512
  // split-K partials live in d_out's out_rec region (written later by G7)
  float* partial = out_rec;  // [8][2048][1024] f32 = 67 MB

  static bool attrDone = false;
  if (!attrDone) {
    (void)hipFuncSetAttribute(reinterpret_cast<const void*>(&gemm256<0, false>),
                              hipFuncAttributeMaxDynamicSharedMemorySize, 131072);
    (void)hipFuncSetAttribute(reinterpret_cast<const void*>(&gemm256<2, false>),
                              hipFuncAttributeMaxDynamicSharedMemorySize, 131072);
    attrDone = true;
  }

  // popular + noisy cast (fused; one pass over likes; zero K-pad)
  hipMemsetAsync(out_pop, 0, I_DIM * sizeof(float), stream);
  noisy_popular_kernel<<<dim3(IPAD / 4 / 256, B_DIM / 64), 256, 0, stream>>>(
      likes, mask, A_noisy, out_pop);

  // ---- encoder layer 1: 256^2 8-phase, split-K=8 (chunks of 2560), f32 partials
  transpose_to_bf16<<<dim3(H_DIM / 32, IPAD / 32), dim3(32, 8), 0, stream>>>(
      enc_w1, W1T, IPAD, H_DIM, I_DIM);
  gemm256<0, false><<<dim3(H_DIM / 256, B_DIM / 256, 8), 512, 131072, stream>>>(
      A_noisy, W1T, nullptr, partial, H_DIM, IPAD, IPAD, H_DIM, IPAD / 8,
      (long long)B_DIM * H_DIM);
  reduce_relu_kernel<8><<<B_DIM * H_DIM / 4 / 256, 256, 0, stream>>>(partial,
                                                                     enc_b1, h1);

  // ---- encoder layer 2
  transpose_to_bf16<<<dim3(D_DIM / 32, H_DIM / 32), dim3(32, 8), 0, stream>>>(
      enc_w2, W2T, H_DIM, D_DIM, H_DIM);
  gemm128<1, true><<<dim3(D_DIM / 128, B_DIM / 128, 1), 256, 0, stream>>>(
      h1, W2T, enc_b2, embed, D_DIM, H_DIM, H_DIM, D_DIM, H_DIM, 0);

  // ---- cosine-similarity gram
  l2norm_kernel<<<B_DIM / 4, 256, 0, stream>>>(embed, normed);
  gemm128<3, false><<<dim3(B_DIM / 128, B_DIM / 128, 1), 256, 0, stream>>>(
      normed, normed, nullptr, out_sim, B_DIM, D_DIM, D_DIM, B_DIM, D_DIM, 0);

  // ---- heads layer 1 (fused lk|rc): N = 2048
  concat_bias_kernel<<<2 * H_DIM / 256, 256, 0, stream>>>(lk_b1, rc_b1, bcat);
  transpose_to_bf16<<<dim3(H_DIM / 32, D_DIM / 32), dim3(32, 8), 0, stream>>>(
      lk_w1, W1catT, D_DIM, H_DIM, D_DIM);
  transpose_to_bf16<<<dim3(H_DIM / 32, D_DIM / 32), dim3(32, 8), 0, stream>>>(
      rc_w1, W1catT + (size_t)H_DIM * D_DIM, D_DIM, H_DIM, D_DIM);
  gemm128<1, true><<<dim3(2 * H_DIM / 128, B_DIM / 128, 1), 256, 0, stream>>>(
      embed, W1catT, bcat, hboth, 2 * H_DIM, D_DIM, D_DIM, 2 * H_DIM, D_DIM, 0);

  // ---- heads layer 2 (A_noisy region now dead -> LK2T/RC2T), 256^2 8-phase
  transpose_to_bf16<<<dim3(I_DIM / 32, H_DIM / 32), dim3(32, 8), 0, stream>>>(
      lk_w2, LK2T, H_DIM, I_DIM, H_DIM);
  transpose_to_bf16<<<dim3(I_DIM / 32, H_DIM / 32), dim3(32, 8), 0, stream>>>(
      rc_w2, RC2T, H_DIM, I_DIM, H_DIM);
  gemm256<2, false><<<dim3(NPAD / 256, B_DIM / 256, 1), 512, 131072, stream>>>(
      hboth, LK2T, lk_b2, out_likes, I_DIM, 2 * H_DIM, H_DIM, I_DIM, H_DIM, 0);
  gemm256<2, false><<<dim3(NPAD / 256, B_DIM / 256, 1), 512, 131072, stream>>>(
      hboth + H_DIM, RC2T, rc_b2, out_rec, I_DIM, 2 * H_DIM, H_DIM, I_DIM, H_DIM, 0);
}

// Round 4
// 1096.600 us; speedup vs baseline: 1.1711x; 1.0619x over previous
//
#include <hip/hip_runtime.h>
#include <cstdint>
#include <cstddef>

#define B_DIM 2048
#define I_DIM 20000
#define IPAD 20480   // encoder-L1 K padded to multiple of 128 (8 x 2560)
#define NPAD 20224   // heads-L2 N padded to multiple of 256 (79 x 256)
#define D_DIM 512
#define H_DIM 1024   // 2*D

typedef __bf16 bf16x8 __attribute__((ext_vector_type(8)));
typedef float f32x4 __attribute__((ext_vector_type(4)));

__device__ __forceinline__ unsigned short f2bf(float f) {
  union { float f; unsigned u; } v; v.f = f;
  unsigned u = v.u;
  u += 0x7fffu + ((u >> 16) & 1u);  // RNE (finite inputs)
  return (unsigned short)(u >> 16);
}
__device__ __forceinline__ float bf2f(unsigned short h) {
  union { unsigned u; float f; } v; v.u = ((unsigned)h) << 16;
  return v.f;
}

// async global->LDS, 16B per lane; lds dest = wave-uniform base + lane*16
__device__ __forceinline__ void glds16(const unsigned short* g, unsigned short* l) {
  __builtin_amdgcn_global_load_lds(
      (const __attribute__((address_space(1))) void*)g,
      (__attribute__((address_space(3))) void*)l, 16, 0, 0);
}

// ---------------------------------------------------------------------------
// Fused: noisy = mask ? 0 : likes (bf16, K-padded to IPAD with zeros),
// popular += colsum(likes)/B. grid: (IPAD/4/256, B/64), 256 thr.
__global__ void noisy_popular_kernel(const float* __restrict__ likes,
                                     const int* __restrict__ mask,
                                     unsigned short* __restrict__ noisy,
                                     float* __restrict__ pop) {
  int idx4 = blockIdx.x * 256 + threadIdx.x;  // float4 column index, < IPAD/4
  int r0 = blockIdx.y * 64;
  if (idx4 >= I_DIM / 4) {  // zero pad region [5000, 5120)
    ushort4 z = make_ushort4(0, 0, 0, 0);
    for (int r = 0; r < 64; ++r)
      ((ushort4*)noisy)[(size_t)(r0 + r) * (IPAD / 4) + idx4] = z;
    return;
  }
  float4 s = make_float4(0.f, 0.f, 0.f, 0.f);
  for (int r = 0; r < 64; ++r) {
    size_t inoff = (size_t)(r0 + r) * (I_DIM / 4) + idx4;
    float4 L = ((const float4*)likes)[inoff];
    int4 M = ((const int4*)mask)[inoff];
    s.x += L.x; s.y += L.y; s.z += L.z; s.w += L.w;
    ushort4 o;
    o.x = M.x ? (unsigned short)0 : f2bf(L.x);
    o.y = M.y ? (unsigned short)0 : f2bf(L.y);
    o.z = M.z ? (unsigned short)0 : f2bf(L.z);
    o.w = M.w ? (unsigned short)0 : f2bf(L.w);
    ((ushort4*)noisy)[(size_t)(r0 + r) * (IPAD / 4) + idx4] = o;
  }
  const float inv = 1.0f / B_DIM;
  atomicAdd(&pop[idx4 * 4 + 0], s.x * inv);
  atomicAdd(&pop[idx4 * 4 + 1], s.y * inv);
  atomicAdd(&pop[idx4 * 4 + 2], s.z * inv);
  atomicAdd(&pop[idx4 * 4 + 3], s.w * inv);
}

// ---------------------------------------------------------------------------
// transpose f32 [Rvalid,C] -> bf16 [C,Rpad], 64x64 tiles, vectorized:
// float4 loads, ushort4 stores (128B per 16-lane segment).
// grid: (ceil(C/64), Rpad/64), 256 thr. Rows >= Rvalid -> 0. C % 4 == 0.
__global__ void transpose64_to_bf16(const float* __restrict__ in,
                                    unsigned short* __restrict__ out, int Rpad,
                                    int C, int Rvalid) {
  __shared__ unsigned short tile[64][72];  // [c][r], row stride 144B (8B-aligned)
  int c0 = blockIdx.x * 64, r0 = blockIdx.y * 64;
  int t = threadIdx.x;
  int tr = t >> 4;    // 0..15
  int tc4 = t & 15;   // 0..15 (float4 group)
#pragma unroll
  for (int i = 0; i < 4; i++) {
    int r = r0 + tr + 16 * i;
    float4 v = make_float4(0.f, 0.f, 0.f, 0.f);
    if (r < Rvalid && c0 + tc4 * 4 + 3 < C)
      v = *(const float4*)&in[(size_t)r * C + c0 + tc4 * 4];
    tile[tc4 * 4 + 0][tr + 16 * i] = f2bf(v.x);
    tile[tc4 * 4 + 1][tr + 16 * i] = f2bf(v.y);
    tile[tc4 * 4 + 2][tr + 16 * i] = f2bf(v.z);
    tile[tc4 * 4 + 3][tr + 16 * i] = f2bf(v.w);
  }
  __syncthreads();
#pragma unroll
  for (int i = 0; i < 4; i++) {
    int c = c0 + tr + 16 * i;
    if (c < C) {
      ushort4 o = *(const ushort4*)&tile[tr + 16 * i][tc4 * 4];
      *(ushort4*)&out[(size_t)c * Rpad + r0 + tc4 * 4] = o;
    }
  }
}

// ---------------------------------------------------------------------------
__global__ void concat_bias_kernel(const float* __restrict__ a,
                                   const float* __restrict__ b,
                                   float* __restrict__ out) {
  int i = blockIdx.x * 256 + threadIdx.x;
  if (i < H_DIM) out[i] = a[i];
  else if (i < 2 * H_DIM) out[i] = b[i - H_DIM];
}

// ---------------------------------------------------------------------------
// h1 = bf16(relu(sum_z partial[z] + bias))   partial: [Z][B][H] f32
template <int Z>
__global__ void reduce_relu_kernel(const float* __restrict__ partial,
                                   const float* __restrict__ bias,
                                   unsigned short* __restrict__ h1) {
  int idx4 = blockIdx.x * 256 + threadIdx.x;  // float4 index over B*H/4
  const size_t slice = (size_t)B_DIM * H_DIM / 4;
  float4 s = ((const float4*)partial)[idx4];
#pragma unroll
  for (int z = 1; z < Z; z++) {
    float4 p = ((const float4*)partial)[z * slice + idx4];
    s.x += p.x; s.y += p.y; s.z += p.z; s.w += p.w;
  }
  float4 b = ((const float4*)bias)[idx4 & (H_DIM / 4 - 1)];
  ushort4 o;
  o.x = f2bf(fmaxf(s.x + b.x, 0.f));
  o.y = f2bf(fmaxf(s.y + b.y, 0.f));
  o.z = f2bf(fmaxf(s.z + b.z, 0.f));
  o.w = f2bf(fmaxf(s.w + b.w, 0.f));
  ((ushort4*)h1)[idx4] = o;
}

// ---------------------------------------------------------------------------
// L2-normalize rows of embed (bf16 [B, D]) -> normed (bf16)
__global__ void l2norm_kernel(const unsigned short* __restrict__ embed,
                              unsigned short* __restrict__ normed) {
  int row = blockIdx.x * 4 + (threadIdx.x >> 6);
  int lane = threadIdx.x & 63;
  const unsigned short* e = embed + (size_t)row * D_DIM;
  float v[8];
  float ss = 0.f;
#pragma unroll
  for (int j = 0; j < 8; j++) { v[j] = bf2f(e[lane + j * 64]); ss += v[j] * v[j]; }
#pragma unroll
  for (int o = 32; o > 0; o >>= 1) ss += __shfl_xor(ss, o, 64);
  float s = rsqrtf(fmaxf(ss, 1e-12f));
  unsigned short* nr = normed + (size_t)row * D_DIM;
#pragma unroll
  for (int j = 0; j < 8; j++) nr[lane + j * 64] = f2bf(v[j] * s);
}

// ---------------------------------------------------------------------------
// m97-structure GEMM (kept for the small GEMMs): C = act(A @ BT^T + bias)
// 128x128 tile, BK=32, 4 waves.
template <int ACT, bool OBF16>
__global__ __launch_bounds__(256) void gemm128(
    const unsigned short* __restrict__ A, const unsigned short* __restrict__ BT,
    const float* __restrict__ bias, void* __restrict__ Cout,
    int N, int lda, int ldb, int ldc, int kLen, long long zStride) {
  __shared__ unsigned short As[128 * 32];
  __shared__ unsigned short Bs[128 * 32];
  const int n0 = blockIdx.x * 128;
  const int m0 = blockIdx.y * 128;
  const int t = threadIdx.x;
  const int lane = t & 63;
  const int wv = t >> 6;
  const int quad = lane >> 4;
  const int tc = lane & 15;
  const int wm = (wv >> 1) * 64;
  const int wn = (wv & 1) * 64;
  const int k0 = blockIdx.z * kLen;

  f32x4 acc[4][4];
#pragma unroll
  for (int i = 0; i < 4; i++)
#pragma unroll
    for (int j = 0; j < 4; j++) acc[i][j] = (f32x4){0.f, 0.f, 0.f, 0.f};

  const int srow = lane >> 2;
  const int skch = (lane & 3) * 8;
  const unsigned short* gA0 = A + (size_t)(m0 + wv * 32 + srow) * lda + k0 + skch;
  const unsigned short* gA1 = gA0 + (size_t)16 * lda;
  const unsigned short* gB0 = BT + (size_t)(n0 + wv * 32 + srow) * ldb + k0 + skch;
  const unsigned short* gB1 = gB0 + (size_t)16 * ldb;
  unsigned short* lA = As + wv * 1024;
  unsigned short* lB = Bs + wv * 1024;

  const int nIter = kLen >> 5;
  for (int it = 0; it < nIter; ++it) {
    __syncthreads();
    glds16(gA0, lA);
    glds16(gA1, lA + 512);
    glds16(gB0, lB);
    glds16(gB1, lB + 512);
    gA0 += 32; gA1 += 32; gB0 += 32; gB1 += 32;
    __syncthreads();
    bf16x8 a[4], b[4];
#pragma unroll
    for (int i = 0; i < 4; i++) {
      a[i] = *(const bf16x8*)&As[(wm + i * 16 + tc) * 32 + quad * 8];
      b[i] = *(const bf16x8*)&Bs[(wn + i * 16 + tc) * 32 + quad * 8];
    }
#pragma unroll
    for (int i = 0; i < 4; i++)
#pragma unroll
      for (int j = 0; j < 4; j++)
        acc[i][j] =
            __builtin_amdgcn_mfma_f32_16x16x32_bf16(a[i], b[j], acc[i][j], 0, 0, 0);
  }

  float* outF = (float*)Cout + (size_t)blockIdx.z * zStride;
  unsigned short* outH = (unsigned short*)Cout;
#pragma unroll
  for (int j = 0; j < 4; j++) {
    int col = n0 + wn + j * 16 + tc;
    if (col >= N) continue;
    float bv = bias ? bias[col] : 0.f;
#pragma unroll
    for (int i = 0; i < 4; i++) {
      int row0 = m0 + wm + i * 16 + quad * 4;
#pragma unroll
      for (int r = 0; r < 4; r++) {
        float v = acc[i][j][r] + bv;
        if (ACT == 1) v = fmaxf(v, 0.f);
        else if (ACT == 2) v = 1.f / (1.f + __expf(-v));
        else if (ACT == 3) v = -v;
        if (OBF16)
          outH[(size_t)(row0 + r) * ldc + col] = f2bf(v);
        else
          outF[(size_t)(row0 + r) * ldc + col] = v;
      }
    }
  }
}

// ---------------------------------------------------------------------------
// 256x256 8-phase GEMM (m201-style: T2 LDS XOR-swizzle + T3/T4 counted vmcnt
// + T5 setprio). 16x16x32 MFMA (round-1-proven core). BK=64, 8 waves (2Mx4N),
// 128 KiB dynamic LDS, 2 K-tiles/iter. Staging via global_load_lds with
// PRE-SWIZZLED global source (slot ^= row&7), linear LDS dest; ds_read
// applies the same XOR (rule #21 both-sides-or-neither).
// DUAL: blockIdx.z selects {A col-half, BT half, bias, out} (fused G6/G7);
// else blockIdx.z = split-K chunk writing f32 partial at z*zStride.
// Requires: M%256==0, BT padded to 256-row blocks, kLen%128==0.
template <int ACT, bool OBF16, bool DUAL>
__global__ __launch_bounds__(512, 2) void gemm256(
    const unsigned short* __restrict__ A, const unsigned short* __restrict__ BT,
    const float* __restrict__ bias, void* __restrict__ Cout,
    int N, int lda, int ldb, int ldc, int kLen, long long zStride,
    const float* __restrict__ bias2, void* __restrict__ Cout2) {
  extern __shared__ unsigned short lds[];
  if (DUAL && blockIdx.z) {
    A += H_DIM;                      // second col-half of hboth
    BT += (size_t)NPAD * ldb;        // RC2T follows LK2T
    bias = bias2;
    Cout = Cout2;
  }
  const int n0 = blockIdx.x * 256;
  const int m0 = blockIdx.y * 256;
  const int t = threadIdx.x;
  const int L = t & 63;
  const int w = t >> 6;
  const int quad = L >> 4;
  const int tc = L & 15;
  const int wm = (w >> 2) * 128;  // 0 / 128
  const int wn = (w & 3) * 64;    // 0,64,128,192
  const int k0 = DUAL ? 0 : blockIdx.z * kLen;

  // staging: per phase one 128x64 half-tile (16 KB). wave w covers rows
  // [w*16, w*16+16); lane L -> row +(L>>3), 16B slot (L&7), global slot
  // pre-swizzled by ^(row&7) = ^(L>>3).
  const int srow = L >> 3;
  const int scol = ((L & 7) ^ srow) * 8;  // elems
  size_t aOff[2][2], bOff[2][2];
#pragma unroll
  for (int h = 0; h < 2; h++)
#pragma unroll
    for (int c = 0; c < 2; c++) {
      aOff[h][c] = (size_t)(m0 + h * 128 + w * 16 + c * 8 + srow) * lda + k0 + scol;
      bOff[h][c] = (size_t)(n0 + h * 128 + w * 16 + c * 8 + srow) * ldb + k0 + scol;
    }
  const int stageW = w * 1024;  // ushorts (16 rows x 64)
  const int BO1 = 32768;        // buf1 offset (64 KB)

  const int aR0 = (wm >> 7) * 8192;          // own A-half slot, buf0
  const int aR1 = BO1 + aR0;
  const int bR0 = 16384 + (wn >> 7) * 8192;  // own B-half slot, buf0
  const int bR1 = BO1 + bR0;
  const int swz = (tc & 7) << 3;  // read-side XOR (row&7 == tc&7 for frag rows)

  f32x4 acc[8][4];
#pragma unroll
  for (int i = 0; i < 8; i++)
#pragma unroll
    for (int j = 0; j < 4; j++) acc[i][j] = (f32x4){0.f, 0.f, 0.f, 0.f};

  bf16x8 aF[4][2], bF0[2][2], bF1[2][2];

#define STAGE_A(h, kt, bo)                                                        \
  do {                                                                            \
    glds16(A + aOff[h][0] + (size_t)(kt) * 64, lds + (bo) + (h) * 8192 + stageW); \
    glds16(A + aOff[h][1] + (size_t)(kt) * 64,                                    \
           lds + (bo) + (h) * 8192 + stageW + 512);                               \
  } while (0)
#define STAGE_B(h, kt, bo)                                                        \
  do {                                                                            \
    glds16(BT + bOff[h][0] + (size_t)(kt) * 64,                                   \
           lds + (bo) + 16384 + (h) * 8192 + stageW);                             \
    glds16(BT + bOff[h][1] + (size_t)(kt) * 64,                                   \
           lds + (bo) + 16384 + (h) * 8192 + stageW + 512);                       \
  } while (0)

  auto RD_A = [&](int base, int i0) {
#pragma unroll
    for (int ii = 0; ii < 4; ii++) {
      const int row = (i0 + ii) * 16 + tc;
#pragma unroll
      for (int ks = 0; ks < 2; ks++)
        aF[ii][ks] =
            *(const bf16x8*)&lds[base + row * 64 + (((ks * 4 + quad) * 8) ^ swz)];
    }
  };
  auto RD_B = [&](int base, int jg, bf16x8(&bF)[2][2]) {
#pragma unroll
    for (int jj = 0; jj < 2; jj++) {
      const int row = (wn & 64) + (jg * 2 + jj) * 16 + tc;
#pragma unroll
      for (int ks = 0; ks < 2; ks++)
        bF[jj][ks] =
            *(const bf16x8*)&lds[base + row * 64 + (((ks * 4 + quad) * 8) ^ swz)];
    }
  };
  auto MM = [&](int ig, bf16x8(&bF)[2][2], int jg) {
#pragma unroll
    for (int ii = 0; ii < 4; ii++)
#pragma unroll
      for (int jj = 0; jj < 2; jj++)
#pragma unroll
        for (int ks = 0; ks < 2; ks++)
          acc[ig * 4 + ii][jg * 2 + jj] = __builtin_amdgcn_mfma_f32_16x16x32_bf16(
              aF[ii][ks], bF[jj][ks], acc[ig * 4 + ii][jg * 2 + jj], 0, 0, 0);
  };

#define PH_MID()                                      \
  __builtin_amdgcn_s_barrier();                       \
  asm volatile("s_waitcnt lgkmcnt(0)" ::: "memory");  \
  __builtin_amdgcn_sched_barrier(0);                  \
  __builtin_amdgcn_s_setprio(1)
#define PH_END()                                      \
  __builtin_amdgcn_s_setprio(0);                      \
  __builtin_amdgcn_sched_barrier(0);                  \
  __builtin_amdgcn_s_barrier()
#define VMW4() asm volatile("s_waitcnt vmcnt(4)" ::: "memory")

  const int nT = kLen >> 6;   // K-tiles of 64 (even)
  const int nIt = nT >> 1;

  // prologue: tile0 A+B -> buf0, tile1 B -> buf1; allow tile1-B in flight
  STAGE_A(0, 0, 0); STAGE_A(1, 0, 0); STAGE_B(0, 0, 0); STAGE_B(1, 0, 0);
  STAGE_B(0, 1, BO1); STAGE_B(1, 1, BO1);
  VMW4();
  __builtin_amdgcn_s_barrier();

#pragma unroll 1
  for (int it = 0; it < nIt; ++it) {
    const int T = it << 1;
    const int ktA1 = T + 1;                         // always valid
    const int kt2 = (T + 2 < nT) ? T + 2 : nT - 1;  // tail: dummy re-stage
    const int kt3 = (T + 3 < nT) ? T + 3 : nT - 1;
    // p0: compute T (buf0) quadrant i0-3 x j0-1
    RD_A(aR0, 0); RD_B(bR0, 0, bF0);
    STAGE_A(0, ktA1, BO1);
    PH_MID(); MM(0, bF0, 0); PH_END();
    // p1: i0-3 x j2-3
    RD_B(bR0, 1, bF1);
    STAGE_A(1, ktA1, BO1);
    PH_MID(); MM(0, bF1, 1); PH_END();
    // p2: i4-7 x j0-1   (T's B0 reads finished end-p1 -> safe to stage B into buf0)
    RD_A(aR0, 4);
    STAGE_B(0, kt2, 0);
    PH_MID(); MM(1, bF0, 0); PH_END();
    // p3: i4-7 x j2-3; counted wait: T+1's A (p0/p1) + B (prev p6/p7) landed
    STAGE_B(1, kt2, 0);
    PH_MID(); MM(1, bF1, 1); VMW4(); PH_END();
    // p4: compute T+1 (buf1) i0-3 x j0-1  (T's A reads finished end-p2)
    RD_A(aR1, 0); RD_B(bR1, 0, bF0);
    STAGE_A(0, kt2, 0);
    PH_MID(); MM(0, bF0, 0); PH_END();
    // p5: i0-3 x j2-3
    RD_B(bR1, 1, bF1);
    STAGE_A(1, kt2, 0);
    PH_MID(); MM(0, bF1, 1); PH_END();
    // p6: i4-7 x j0-1  (T+1's B reads finished end-p5 -> stage B into buf1)
    RD_A(aR1, 4);
    STAGE_B(0, kt3, BO1);
    PH_MID(); MM(1, bF0, 0); PH_END();
    // p7: i4-7 x j2-3; counted wait: T+2's B (p2/p3) + A (p4/p5) landed
    STAGE_B(1, kt3, BO1);
    PH_MID(); MM(1, bF1, 1); VMW4(); PH_END();
  }
#undef STAGE_A
#undef STAGE_B
#undef PH_MID
#undef PH_END
#undef VMW4

  float* outF = (float*)Cout + (size_t)(DUAL ? 0 : blockIdx.z * zStride);
  unsigned short* outH = (unsigned short*)Cout;
#pragma unroll
  for (int j = 0; j < 4; j++) {
    const int col = n0 + wn + j * 16 + tc;
    if (col >= N) continue;
    const float bv = bias ? bias[col] : 0.f;
#pragma unroll
    for (int i = 0; i < 8; i++) {
      const int row0 = m0 + wm + i * 16 + quad * 4;
#pragma unroll
      for (int r = 0; r < 4; r++) {
        float v = acc[i][j][r] + bv;
        if (ACT == 1) v = fmaxf(v, 0.f);
        else if (ACT == 2) v = 1.f / (1.f + __expf(-v));
        else if (ACT == 3) v = -v;
        if (OBF16)
          outH[(size_t)row0 * ldc + (size_t)r * ldc + col] = f2bf(v);
        else
          outF[(size_t)(row0 + r) * ldc + col] = v;
      }
    }
  }
}

// ---------------------------------------------------------------------------
extern "C" void kernel_launch(void* const* d_in, const int* in_sizes, int n_in,
                              void* d_out, int out_size, void* d_ws, size_t ws_size,
                              hipStream_t stream) {
  const float* likes = (const float*)d_in[1];
  const int* mask = (const int*)d_in[2];
  const float* enc_w1 = (const float*)d_in[3];
  const float* enc_b1 = (const float*)d_in[4];
  const float* enc_w2 = (const float*)d_in[5];
  const float* enc_b2 = (const float*)d_in[6];
  const float* lk_w1 = (const float*)d_in[7];
  const float* lk_b1 = (const float*)d_in[8];
  const float* lk_w2 = (const float*)d_in[9];
  const float* lk_b2 = (const float*)d_in[10];
  const float* rc_w1 = (const float*)d_in[11];
  const float* rc_b1 = (const float*)d_in[12];
  const float* rc_w2 = (const float*)d_in[13];
  const float* rc_b2 = (const float*)d_in[14];

  float* out_likes = (float*)d_out;
  float* out_sim = out_likes + (size_t)B_DIM * I_DIM;
  float* out_rec = out_sim + (size_t)B_DIM * B_DIM;
  float* out_pop = out_rec + (size_t)B_DIM * I_DIM;

  // ws layout (ushort units). A_noisy region reused by LK2T/RC2T after G1.
  unsigned short* ws = (unsigned short*)d_ws;
  unsigned short* A_noisy = ws;                              // 2048 x 20480
  unsigned short* LK2T = ws;                                 // 20224 x 1024
  unsigned short* RC2T = ws + (size_t)NPAD * H_DIM;          // 20224 x 1024
  unsigned short* W1T = ws + (size_t)B_DIM * IPAD;           // 1024 x 20480
  unsigned short* W2T = W1T + (size_t)H_DIM * IPAD;          // 512 x 1024
  unsigned short* W1catT = W2T + (size_t)D_DIM * H_DIM;      // 2048 x 512
  float* bcat = (float*)(W1catT + (size_t)2 * H_DIM * D_DIM);  // 2048 f32
  unsigned short* h1 = W1catT + (size_t)2 * H_DIM * D_DIM + 2 * H_DIM * 2;
  unsigned short* hboth = h1 + (size_t)B_DIM * H_DIM;        // 2048 x 2048
  unsigned short* embed = hboth + (size_t)B_DIM * 2 * H_DIM; // 2048 x 512
  unsigned short* normed = embed + (size_t)B_DIM * D_DIM;    // 2048 x 512
  // split-K partials live in d_out's out_rec region (written later by G7)
  float* partial = out_rec;  // [8][2048][1024] f32 = 67 MB

  static bool attrDone = false;
  if (!attrDone) {
    (void)hipFuncSetAttribute(
        reinterpret_cast<const void*>(&gemm256<0, false, false>),
        hipFuncAttributeMaxDynamicSharedMemorySize, 131072);
    (void)hipFuncSetAttribute(
        reinterpret_cast<const void*>(&gemm256<2, false, true>),
        hipFuncAttributeMaxDynamicSharedMemorySize, 131072);
    attrDone = true;
  }

  // popular + noisy cast (fused; one pass over likes; zero K-pad)
  hipMemsetAsync(out_pop, 0, I_DIM * sizeof(float), stream);
  noisy_popular_kernel<<<dim3(IPAD / 4 / 256, B_DIM / 64), 256, 0, stream>>>(
      likes, mask, A_noisy, out_pop);

  // ---- encoder layer 1: 256^2 8-phase, split-K=8 (chunks of 2560), f32 partials
  transpose64_to_bf16<<<dim3(H_DIM / 64, IPAD / 64), 256, 0, stream>>>(
      enc_w1, W1T, IPAD, H_DIM, I_DIM);
  gemm256<0, false, false>
      <<<dim3(H_DIM / 256, B_DIM / 256, 8), 512, 131072, stream>>>(
          A_noisy, W1T, nullptr, partial, H_DIM, IPAD, IPAD, H_DIM, IPAD / 8,
          (long long)B_DIM * H_DIM, nullptr, nullptr);
  reduce_relu_kernel<8><<<B_DIM * H_DIM / 4 / 256, 256, 0, stream>>>(partial,
                                                                     enc_b1, h1);

  // ---- encoder layer 2
  transpose64_to_bf16<<<dim3(D_DIM / 64, H_DIM / 64), 256, 0, stream>>>(
      enc_w2, W2T, H_DIM, D_DIM, H_DIM);
  gemm128<1, true><<<dim3(D_DIM / 128, B_DIM / 128, 1), 256, 0, stream>>>(
      h1, W2T, enc_b2, embed, D_DIM, H_DIM, H_DIM, D_DIM, H_DIM, 0);

  // ---- cosine-similarity gram
  l2norm_kernel<<<B_DIM / 4, 256, 0, stream>>>(embed, normed);
  gemm128<3, false><<<dim3(B_DIM / 128, B_DIM / 128, 1), 256, 0, stream>>>(
      normed, normed, nullptr, out_sim, B_DIM, D_DIM, D_DIM, B_DIM, D_DIM, 0);

  // ---- heads layer 1 (fused lk|rc): N = 2048
  concat_bias_kernel<<<2 * H_DIM / 256, 256, 0, stream>>>(lk_b1, rc_b1, bcat);
  transpose64_to_bf16<<<dim3(H_DIM / 64, D_DIM / 64), 256, 0, stream>>>(
      lk_w1, W1catT, D_DIM, H_DIM, D_DIM);
  transpose64_to_bf16<<<dim3(H_DIM / 64, D_DIM / 64), 256, 0, stream>>>(
      rc_w1, W1catT + (size_t)H_DIM * D_DIM, D_DIM, H_DIM, D_DIM);
  gemm128<1, true><<<dim3(2 * H_DIM / 128, B_DIM / 128, 1), 256, 0, stream>>>(
      embed, W1catT, bcat, hboth, 2 * H_DIM, D_DIM, D_DIM, 2 * H_DIM, D_DIM, 0);

  // ---- heads layer 2, fused lk+rc via blockIdx.z (one launch, 1264 blocks)
  transpose64_to_bf16<<<dim3((I_DIM + 63) / 64, H_DIM / 64), 256, 0, stream>>>(
      lk_w2, LK2T, H_DIM, I_DIM, H_DIM);
  transpose64_to_bf16<<<dim3((I_DIM + 63) / 64, H_DIM / 64), 256, 0, stream>>>(
      rc_w2, RC2T, H_DIM, I_DIM, H_DIM);
  gemm256<2, false, true>
      <<<dim3(NPAD / 256, B_DIM / 256, 2), 512, 131072, stream>>>(
          hboth, LK2T, lk_b2, out_likes, I_DIM, 2 * H_DIM, H_DIM, I_DIM, H_DIM,
          0, rc_b2, out_rec);
}